// Round 18
// baseline (876.465 us; speedup 1.0000x reference)
//
#include <hip/hip_runtime.h>
#include <cstdint>
#include <cstddef>

// ---------------------------------------------------------------------------
// Sizes: BATCH=8192, INPUT_DIM=512, DIM=64, N_EMB=4096, M_BOOK=4
// d_out (fp32): x_hat[8192*512] | ze[4*8192*64] | ce[4*8192*64]
// Bit-exact numpy-fp32 mimic (identical FP op sequence per output to rounds
// 6-17).  This round: (1) l1 shared-prefix factoring (the q-only chain
// segment before book m's patch is row-independent -> computed once, exact
// same per-accumulator op order); (2) dist processes 4 codes/iter (16
// accumulator chains, min-update still strictly k-ascending).
// ---------------------------------------------------------------------------

#define FMUL __fmul_rn
#define FADD __fadd_rn
#define FSUB __fsub_rn
#define DSPLIT 16
#define KEEP4(v) asm volatile("" : "+v"(v.x), "+v"(v.y), "+v"(v.z), "+v"(v.w))

// ---- L1 mimic: 32 rows/block, shared q-prefix -> h1T[m][h][n] ---------------
__global__ __launch_bounds__(256) void l1_mimic_k(
    const float* __restrict__ x, const float* __restrict__ qt,
    const float* __restrict__ eW1, const float* __restrict__ eb1,
    float* __restrict__ h1T)
{
  __shared__ float xL[32 * 128];
  __shared__ float qtL[512];
  const int m = blockIdx.y;
  const int t = threadIdx.x;
  const int h = t & 127, ngl = t >> 7;          // 2 groups x 16 rows
  const int n0 = blockIdx.x * 32;
  if (t < 128)
    *(float4*)&qtL[t * 4] = *(const float4*)(qt + (size_t)m * 512 + t * 4);
  for (int f4 = t; f4 < 1024; f4 += 256) {      // 32 rows x 128 cols / 4
    int r = f4 >> 5, c4 = (f4 & 31) * 4;
    *(float4*)&xL[r * 128 + c4] =
        *(const float4*)(x + (size_t)(n0 + r) * 512 + m * 128 + c4);
  }
  __syncthreads();
  const float* W1m = eW1 + (size_t)m * 65536;
  const int rbase = ngl * 16;
  const int e0 = m * 128;

  // shared prefix: e in [0, m*128), q-only terms (row-independent chain)
  float pref = 0.f;
  for (int e = 0; e < e0; e += 4) {
    float w0 = W1m[(e + 0) * 128 + h];
    float w1 = W1m[(e + 1) * 128 + h];
    float w2 = W1m[(e + 2) * 128 + h];
    float w3 = W1m[(e + 3) * 128 + h];
    float4 q4 = *(const float4*)&qtL[e];
    pref = FADD(pref, FMUL(q4.x, w0));
    pref = FADD(pref, FMUL(q4.y, w1));
    pref = FADD(pref, FMUL(q4.z, w2));
    pref = FADD(pref, FMUL(q4.w, w3));
  }
  float acc[16];
  #pragma unroll
  for (int r = 0; r < 16; ++r) acc[r] = pref;

  // patch segment: e in [m*128, m*128+128) -> row-specific x-terms
  for (int eo = 0; eo < 128; eo += 4) {
    const int e = e0 + eo;
    float w0 = W1m[(e + 0) * 128 + h];
    float w1 = W1m[(e + 1) * 128 + h];
    float w2 = W1m[(e + 2) * 128 + h];
    float w3 = W1m[(e + 3) * 128 + h];
    float4 q4 = *(const float4*)&qtL[e];
    #pragma unroll
    for (int r = 0; r < 16; ++r) {              // chain order: e ascending
      float4 x4 = *(const float4*)&xL[(rbase + r) * 128 + eo];
      acc[r] = FADD(acc[r], FMUL(FADD(x4.x, q4.x), w0));
      acc[r] = FADD(acc[r], FMUL(FADD(x4.y, q4.y), w1));
      acc[r] = FADD(acc[r], FMUL(FADD(x4.z, q4.z), w2));
      acc[r] = FADD(acc[r], FMUL(FADD(x4.w, q4.w), w3));
    }
  }

  // suffix: e in [m*128+128, 512), q-only addends (per-row chains continue)
  for (int e = e0 + 128; e < 512; e += 4) {
    float w0 = W1m[(e + 0) * 128 + h];
    float w1 = W1m[(e + 1) * 128 + h];
    float w2 = W1m[(e + 2) * 128 + h];
    float w3 = W1m[(e + 3) * 128 + h];
    float4 q4 = *(const float4*)&qtL[e];
    #pragma unroll
    for (int r = 0; r < 16; ++r) {
      acc[r] = FADD(acc[r], FMUL(q4.x, w0));
      acc[r] = FADD(acc[r], FMUL(q4.y, w1));
      acc[r] = FADD(acc[r], FMUL(q4.z, w2));
      acc[r] = FADD(acc[r], FMUL(q4.w, w3));
    }
  }

  float b = eb1[m * 128 + h];
  float* oT = h1T + ((size_t)(m * 128 + h)) * 8192 + n0 + rbase;
  #pragma unroll
  for (int j = 0; j < 4; ++j) {
    float4 o = {FADD(acc[4 * j + 0], b), FADD(acc[4 * j + 1], b),
                FADD(acc[4 * j + 2], b), FADD(acc[4 * j + 3], b)};
    *(float4*)(oT + 4 * j) = o;
  }
}

// ---- L2 GEMM mimic: OUTC=256, K=128, 16 rows/block, BN fused, out transposed
__global__ __launch_bounds__(256) void seq_mm2_k(
    const float* __restrict__ AT, const float* __restrict__ W,
    const float* __restrict__ b, float* __restrict__ outT,
    const float* __restrict__ mu, const float* __restrict__ rsq,
    const float* __restrict__ g, const float* __restrict__ beta)
{
  __shared__ float aL[16 * 128];
  const int m = blockIdx.y;
  const int t = threadIdx.x;                    // h = t, 0..255
  const int n0 = blockIdx.x * 16;
  const int mK = m * 128;
  for (int f4 = t; f4 < 512; f4 += 256) {
    int c = f4 & 127, r4 = f4 >> 7;
    float4 v = *(const float4*)(AT + (size_t)(mK + c) * 8192 + n0 + r4 * 4);
    float muv = mu[mK + c], rs = rsq[mK + c];
    float gg = g[mK + c], bt = beta[mK + c];
    v.x = fmaxf(FADD(FMUL(FMUL(FSUB(v.x, muv), rs), gg), bt), 0.f);
    v.y = fmaxf(FADD(FMUL(FMUL(FSUB(v.y, muv), rs), gg), bt), 0.f);
    v.z = fmaxf(FADD(FMUL(FMUL(FSUB(v.z, muv), rs), gg), bt), 0.f);
    v.w = fmaxf(FADD(FMUL(FMUL(FSUB(v.w, muv), rs), gg), bt), 0.f);
    aL[(r4 * 4 + 0) * 128 + c] = v.x;
    aL[(r4 * 4 + 1) * 128 + c] = v.y;
    aL[(r4 * 4 + 2) * 128 + c] = v.z;
    aL[(r4 * 4 + 3) * 128 + c] = v.w;
  }
  __syncthreads();
  const float* Wm = W + (size_t)m * 32768;
  float acc[16];
  #pragma unroll
  for (int r = 0; r < 16; ++r) acc[r] = 0.f;
  float w0n = Wm[t], w1n = Wm[256 + t], w2n = Wm[512 + t], w3n = Wm[768 + t];
  for (int e = 0; e < 128; e += 4) {
    float w0 = w0n, w1 = w1n, w2 = w2n, w3 = w3n;
    if (e < 124) {
      w0n = Wm[(e + 4) * 256 + t];
      w1n = Wm[(e + 5) * 256 + t];
      w2n = Wm[(e + 6) * 256 + t];
      w3n = Wm[(e + 7) * 256 + t];
    }
    #pragma unroll
    for (int r = 0; r < 16; ++r) {              // chain order: e ascending
      float4 a4 = *(const float4*)&aL[r * 128 + e];
      acc[r] = FADD(acc[r], FMUL(a4.x, w0));
      acc[r] = FADD(acc[r], FMUL(a4.y, w1));
      acc[r] = FADD(acc[r], FMUL(a4.z, w2));
      acc[r] = FADD(acc[r], FMUL(a4.w, w3));
    }
  }
  float bb = b[m * 256 + t];
  float* oT = outT + (size_t)(m * 256 + t) * 8192 + n0;
  #pragma unroll
  for (int j = 0; j < 4; ++j) {
    float4 o = {FADD(acc[4 * j + 0], bb), FADD(acc[4 * j + 1], bb),
                FADD(acc[4 * j + 2], bb), FADD(acc[4 * j + 3], bb)};
    *(float4*)(oT + 4 * j) = o;
  }
}

// ---- L3 GEMM mimic (generic): from transposed A, BN fused, row-major out ---
template <int OUTC, int K, int RG>
__global__ __launch_bounds__(256) void seq_mm_k(
    const float* __restrict__ AT, const float* __restrict__ W,
    const float* __restrict__ b, float* __restrict__ out,
    long w_bs, long b_bs, long o_bs,
    const float* __restrict__ mu, const float* __restrict__ rsq,
    const float* __restrict__ g, const float* __restrict__ beta)
{
  __shared__ float aL[RG * 8 * K];
  const int m = blockIdx.y;
  const int t = threadIdx.x;
  const int h = t % OUTC, ngl = t / OUTC;
  const int n0 = blockIdx.x * RG * 8;
  const int mK = m * K;
  for (int f4 = t; f4 < K * 2 * RG; f4 += 256) {
    int c = f4 % K, r4 = f4 / K;
    float4 v = *(const float4*)(AT + (size_t)(mK + c) * 8192 + n0 + r4 * 4);
    float muv = mu[mK + c], rs = rsq[mK + c];
    float gg = g[mK + c], bt = beta[mK + c];
    v.x = fmaxf(FADD(FMUL(FMUL(FSUB(v.x, muv), rs), gg), bt), 0.f);
    v.y = fmaxf(FADD(FMUL(FMUL(FSUB(v.y, muv), rs), gg), bt), 0.f);
    v.z = fmaxf(FADD(FMUL(FMUL(FSUB(v.z, muv), rs), gg), bt), 0.f);
    v.w = fmaxf(FADD(FMUL(FMUL(FSUB(v.w, muv), rs), gg), bt), 0.f);
    aL[(r4 * 4 + 0) * K + c] = v.x;
    aL[(r4 * 4 + 1) * K + c] = v.y;
    aL[(r4 * 4 + 2) * K + c] = v.z;
    aL[(r4 * 4 + 3) * K + c] = v.w;
  }
  __syncthreads();
  const float* Wm = W + (size_t)m * w_bs;
  float acc[8] = {0.f,0.f,0.f,0.f,0.f,0.f,0.f,0.f};
  float w0n = Wm[h], w1n = Wm[OUTC + h], w2n = Wm[2 * OUTC + h],
        w3n = Wm[3 * OUTC + h];
  for (int e = 0; e < K; e += 4) {
    float w0 = w0n, w1 = w1n, w2 = w2n, w3 = w3n;
    if (e < K - 4) {
      w0n = Wm[(e + 4) * OUTC + h];
      w1n = Wm[(e + 5) * OUTC + h];
      w2n = Wm[(e + 6) * OUTC + h];
      w3n = Wm[(e + 7) * OUTC + h];
    }
    float4 a4[8];
    #pragma unroll
    for (int r = 0; r < 8; ++r)
      a4[r] = *(const float4*)&aL[(ngl * 8 + r) * K + e];
    #pragma unroll
    for (int r = 0; r < 8; ++r) {               // chain order: e ascending
      acc[r] = FADD(acc[r], FMUL(a4[r].x, w0));
      acc[r] = FADD(acc[r], FMUL(a4[r].y, w1));
      acc[r] = FADD(acc[r], FMUL(a4[r].z, w2));
      acc[r] = FADD(acc[r], FMUL(a4[r].w, w3));
    }
  }
  float bb = b[(size_t)m * b_bs + h];
  #pragma unroll
  for (int r = 0; r < 8; ++r)
    out[(size_t)m * o_bs + (size_t)(n0 + ngl * 8 + r) * OUTC + h] =
        FADD(acc[r], bb);
}

// ---- BN stats from transposed h: contiguous column staged to LDS -----------
__global__ __launch_bounds__(256) void bn_stats_t(
    const float* __restrict__ hT, int K,
    float* __restrict__ mu, float* __restrict__ rsq)
{
  __shared__ float colL[8192];
  const int c = blockIdx.x, m = blockIdx.y;
  const float4* src = (const float4*)(hT + (size_t)(m * K + c) * 8192);
  for (int i = threadIdx.x; i < 2048; i += 256)
    ((float4*)colL)[i] = src[i];
  __syncthreads();
  if (threadIdx.x == 0) {
    float s = 0.f;
    for (int n = 0; n < 8192; ++n) s = FADD(s, colL[n]);
    float muv = __fdiv_rn(s, 8192.f);
    float q = 0.f;
    for (int n = 0; n < 8192; ++n) {
      float d = FSUB(colL[n], muv);
      q = FADD(q, FMUL(d, d));
    }
    float var = __fdiv_rn(q, 8192.f);
    mu[m * K + c] = muv;
    rsq[m * K + c] = __fdiv_rn(1.f, __fsqrt_rn(FADD(var, 1e-5f)));
  }
}

// ---- cnorm mimic: numpy pairwise 8-accumulator sum of c^2 ------------------
__global__ __launch_bounds__(256) void cnorm_mimic_k(
    const float* __restrict__ cb, float* __restrict__ cn)
{
  int o = blockIdx.x * 256 + threadIdx.x;
  const float* c = cb + (size_t)o * 64;
  float r[8];
  #pragma unroll
  for (int j = 0; j < 8; ++j) r[j] = FMUL(c[j], c[j]);
  for (int t = 1; t < 8; ++t)
    #pragma unroll
    for (int j = 0; j < 8; ++j)
      r[j] = FADD(r[j], FMUL(c[8 * t + j], c[8 * t + j]));
  cn[o] = FADD(FADD(FADD(r[0], r[1]), FADD(r[2], r[3])),
               FADD(FADD(r[4], r[5]), FADD(r[6], r[7])));
}

// ---- distance + argmin mimic: GLOBAL code reads, z in regs, 4 codes/iter ---
__global__ __launch_bounds__(256, 4) void dist_mimic_k(
    const float* __restrict__ ze, const float* __restrict__ cb,
    const float* __restrict__ cn, float* __restrict__ pbb,
    int* __restrict__ pbk)
{
  const int t = threadIdx.x;
  const int m = blockIdx.y, seg = blockIdx.z;
  const int n = blockIdx.x * 256 + t;
  const float4* zp4 = (const float4*)(ze + ((size_t)m * 8192 + n) * 64);
  float4 z0 = zp4[0],  z1 = zp4[1],  z2 = zp4[2],  z3 = zp4[3];
  float4 z4 = zp4[4],  z5 = zp4[5],  z6 = zp4[6],  z7 = zp4[7];
  float4 z8 = zp4[8],  z9 = zp4[9],  z10 = zp4[10], z11 = zp4[11];
  float4 z12 = zp4[12], z13 = zp4[13], z14 = zp4[14], z15 = zp4[15];

  // t1 = numpy pairwise-8 sum of squares (identical order since round 6)
  float r0 = FMUL(z0.x, z0.x), r1 = FMUL(z0.y, z0.y);
  float r2 = FMUL(z0.z, z0.z), r3 = FMUL(z0.w, z0.w);
  float r4 = FMUL(z1.x, z1.x), r5 = FMUL(z1.y, z1.y);
  float r6 = FMUL(z1.z, z1.z), r7 = FMUL(z1.w, z1.w);
#define SQ8(ZE, ZO) \
  r0 = FADD(r0, FMUL(ZE.x, ZE.x)); r1 = FADD(r1, FMUL(ZE.y, ZE.y)); \
  r2 = FADD(r2, FMUL(ZE.z, ZE.z)); r3 = FADD(r3, FMUL(ZE.w, ZE.w)); \
  r4 = FADD(r4, FMUL(ZO.x, ZO.x)); r5 = FADD(r5, FMUL(ZO.y, ZO.y)); \
  r6 = FADD(r6, FMUL(ZO.z, ZO.z)); r7 = FADD(r7, FMUL(ZO.w, ZO.w));
  SQ8(z2, z3)  SQ8(z4, z5)  SQ8(z6, z7)
  SQ8(z8, z9)  SQ8(z10, z11) SQ8(z12, z13) SQ8(z14, z15)
#undef SQ8
  const float t1 = FADD(FADD(FADD(r0, r1), FADD(r2, r3)),
                        FADD(FADD(r4, r5), FADD(r6, r7)));

  // force z into registers (defeat rematerialization-from-global)
  KEEP4(z0);  KEEP4(z1);  KEEP4(z2);  KEEP4(z3);
  KEEP4(z4);  KEEP4(z5);  KEEP4(z6);  KEEP4(z7);
  KEEP4(z8);  KEEP4(z9);  KEEP4(z10); KEEP4(z11);
  KEEP4(z12); KEEP4(z13); KEEP4(z14); KEEP4(z15);

  const float* cbm = cb + (size_t)m * 262144;
  const float* cnm = cn + m * 4096;
  float bb = 3.4e38f;
  int bk = 1 << 30;
  const int k0 = seg * (4096 / DSPLIT);
  for (int k = k0; k < k0 + 4096 / DSPLIT; k += 4) {
    const float4* ca4 = (const float4*)(cbm + (size_t)k * 64);
    const float4* cb4 = ca4 + 16;
    const float4* cc4 = ca4 + 32;
    const float4* cd4 = ca4 + 48;
    float A0 = 0.f, A1 = 0.f, A2 = 0.f, A3 = 0.f;
    float B0 = 0.f, B1 = 0.f, B2 = 0.f, B3 = 0.f;
    float C0 = 0.f, C1 = 0.f, C2 = 0.f, C3 = 0.f;
    float D0 = 0.f, D1 = 0.f, D2 = 0.f, D3 = 0.f;
#define DOTSTEP(ZV, S) { \
    float4 ca_ = ca4[S]; float4 cbv_ = cb4[S]; \
    float4 cc_ = cc4[S]; float4 cd_ = cd4[S]; \
    A0 = FADD(A0, FMUL(ZV.x, ca_.x)); B0 = FADD(B0, FMUL(ZV.x, cbv_.x)); \
    C0 = FADD(C0, FMUL(ZV.x, cc_.x)); D0 = FADD(D0, FMUL(ZV.x, cd_.x)); \
    A1 = FADD(A1, FMUL(ZV.y, ca_.y)); B1 = FADD(B1, FMUL(ZV.y, cbv_.y)); \
    C1 = FADD(C1, FMUL(ZV.y, cc_.y)); D1 = FADD(D1, FMUL(ZV.y, cd_.y)); \
    A2 = FADD(A2, FMUL(ZV.z, ca_.z)); B2 = FADD(B2, FMUL(ZV.z, cbv_.z)); \
    C2 = FADD(C2, FMUL(ZV.z, cc_.z)); D2 = FADD(D2, FMUL(ZV.z, cd_.z)); \
    A3 = FADD(A3, FMUL(ZV.w, ca_.w)); B3 = FADD(B3, FMUL(ZV.w, cbv_.w)); \
    C3 = FADD(C3, FMUL(ZV.w, cc_.w)); D3 = FADD(D3, FMUL(ZV.w, cd_.w)); }
    DOTSTEP(z0, 0)   DOTSTEP(z1, 1)   DOTSTEP(z2, 2)   DOTSTEP(z3, 3)
    DOTSTEP(z4, 4)   DOTSTEP(z5, 5)   DOTSTEP(z6, 6)   DOTSTEP(z7, 7)
    DOTSTEP(z8, 8)   DOTSTEP(z9, 9)   DOTSTEP(z10, 10) DOTSTEP(z11, 11)
    DOTSTEP(z12, 12) DOTSTEP(z13, 13) DOTSTEP(z14, 14) DOTSTEP(z15, 15)
#undef DOTSTEP
    float dotA = FADD(FADD(A0, A2), FADD(A1, A3));
    float bA = FADD(FSUB(t1, FMUL(2.f, dotA)), cnm[k]);
    if (bA < bb) { bb = bA; bk = k; }
    float dotB = FADD(FADD(B0, B2), FADD(B1, B3));
    float bB = FADD(FSUB(t1, FMUL(2.f, dotB)), cnm[k + 1]);
    if (bB < bb) { bb = bB; bk = k + 1; }
    float dotC = FADD(FADD(C0, C2), FADD(C1, C3));
    float bC = FADD(FSUB(t1, FMUL(2.f, dotC)), cnm[k + 2]);
    if (bC < bb) { bb = bC; bk = k + 2; }
    float dotD = FADD(FADD(D0, D2), FADD(D1, D3));
    float bD = FADD(FSUB(t1, FMUL(2.f, dotD)), cnm[k + 3]);
    if (bD < bb) { bb = bD; bk = k + 3; }
  }
  size_t o = ((size_t)seg * 4 + m) * 8192 + n;
  pbb[o] = bb;
  pbk[o] = bk;
}

// ---- combine segment partials (ascending seg = ascending k) ----------------
__global__ __launch_bounds__(256) void dist_reduce_k(
    const float* __restrict__ pbb, const int* __restrict__ pbk,
    int* __restrict__ idx)
{
  int i = blockIdx.x * 256 + threadIdx.x;        // 32768 = m*8192+n
  int m = i >> 13, n = i & 8191;
  float bb = pbb[(size_t)m * 8192 + n];
  int bk = pbk[(size_t)m * 8192 + n];
  for (int s = 1; s < DSPLIT; ++s) {
    size_t o = ((size_t)s * 4 + m) * 8192 + n;
    float ob = pbb[o];
    if (ob < bb) { bb = ob; bk = pbk[o]; }
  }
  idx[(size_t)m * 8192 + n] = bk;
}

// ---- gather ce --------------------------------------------------------------
__global__ __launch_bounds__(256) void gather_k(
    const float* __restrict__ cb, const int* __restrict__ idx,
    float* __restrict__ ce)
{
  int t = threadIdx.x;
  int n = blockIdx.x * 16 + (t >> 4);
  int j = t & 15;
  #pragma unroll
  for (int m = 0; m < 4; ++m) {
    int k = idx[(size_t)m * 8192 + n];
    float4 v = *(const float4*)(cb + ((size_t)m * 4096 + k) * 64 + j * 4);
    *(float4*)(ce + ((size_t)m * 8192 + n) * 64 + j * 4) = v;
  }
}

// ---- fast fp32 GEMM (decoder; loose tolerance) ------------------------------
template <int TRANS>
__global__ __launch_bounds__(256) void gemm_k(
    const float* __restrict__ A, int lda, long cst,
    const float* __restrict__ B, int ldb,
    const float* __restrict__ bias,
    const float* __restrict__ ta, const float* __restrict__ tb,
    float* __restrict__ C, int ldc, int K)
{
  __shared__ float As[16][132];
  __shared__ float Bs[16][64];
  const int tid  = threadIdx.x;
  const int row0 = blockIdx.y * 128;
  const int col0 = blockIdx.x * 64;
  const int tr = tid >> 4, tc = tid & 15;
  const int arow = tid >> 2, ak = (tid & 3) * 4;
  const int brow = tid >> 4, bcol = (tid & 15) * 4;

  float acc[8][4];
  #pragma unroll
  for (int i = 0; i < 8; ++i)
    #pragma unroll
    for (int j = 0; j < 4; ++j) acc[i][j] = 0.f;

  for (int k0 = 0; k0 < K; k0 += 16) {
    #pragma unroll
    for (int h = 0; h < 2; ++h) {
      int r = arow + h * 64;
      float4 v;
      if (TRANS == 2) {
        const float* p = A + (size_t)(row0 + r) * lda + k0 + ak;
        float4 u0 = *(const float4*)(p);
        float4 u1 = *(const float4*)(p + cst);
        float4 u2 = *(const float4*)(p + 2 * cst);
        float4 u3 = *(const float4*)(p + 3 * cst);
        v.x = u0.x + u1.x + u2.x + u3.x;
        v.y = u0.y + u1.y + u2.y + u3.y;
        v.z = u0.z + u1.z + u2.z + u3.z;
        v.w = u0.w + u1.w + u2.w + u3.w;
      } else {
        v = *(const float4*)(A + (size_t)(row0 + r) * lda + k0 + ak);
      }
      if (TRANS == 1) {
        v.x = fmaxf(fmaf(ta[k0 + ak + 0], v.x, tb[k0 + ak + 0]), 0.f);
        v.y = fmaxf(fmaf(ta[k0 + ak + 1], v.y, tb[k0 + ak + 1]), 0.f);
        v.z = fmaxf(fmaf(ta[k0 + ak + 2], v.z, tb[k0 + ak + 2]), 0.f);
        v.w = fmaxf(fmaf(ta[k0 + ak + 3], v.w, tb[k0 + ak + 3]), 0.f);
      }
      As[ak + 0][r] = v.x; As[ak + 1][r] = v.y;
      As[ak + 2][r] = v.z; As[ak + 3][r] = v.w;
    }
    *(float4*)&Bs[brow][bcol] =
        *(const float4*)(B + (size_t)(k0 + brow) * ldb + col0 + bcol);
    __syncthreads();
    #pragma unroll
    for (int kk = 0; kk < 16; ++kk) {
      float4 b4 = *(float4*)&Bs[kk][tc * 4];
      float4 a0 = *(float4*)&As[kk][tr * 8];
      float4 a1 = *(float4*)&As[kk][tr * 8 + 4];
      float a8[8] = {a0.x, a0.y, a0.z, a0.w, a1.x, a1.y, a1.z, a1.w};
      #pragma unroll
      for (int i = 0; i < 8; ++i) {
        acc[i][0] = fmaf(a8[i], b4.x, acc[i][0]);
        acc[i][1] = fmaf(a8[i], b4.y, acc[i][1]);
        acc[i][2] = fmaf(a8[i], b4.z, acc[i][2]);
        acc[i][3] = fmaf(a8[i], b4.w, acc[i][3]);
      }
    }
    __syncthreads();
  }
  float4 bv = *(const float4*)(bias + col0 + tc * 4);
  float* Cp = C + (size_t)(row0 + tr * 8) * ldc + col0 + tc * 4;
  #pragma unroll
  for (int i = 0; i < 8; ++i) {
    float4 o;
    o.x = acc[i][0] + bv.x; o.y = acc[i][1] + bv.y;
    o.z = acc[i][2] + bv.z; o.w = acc[i][3] + bv.w;
    *(float4*)(Cp + (size_t)i * ldc) = o;
  }
}

// ---- decoder BN stats: single kernel, one block per column -----------------
__global__ __launch_bounds__(256) void dstats_k(
    const float* __restrict__ A, int cols, const float* __restrict__ g,
    const float* __restrict__ beta, float* __restrict__ ta,
    float* __restrict__ tb)
{
  const int c = blockIdx.x, t = threadIdx.x;
  float s = 0.f, q = 0.f;
  for (int n = t; n < 8192; n += 256) {
    float v = A[(size_t)n * cols + c];
    s += v;
    q = fmaf(v, v, q);
  }
  __shared__ float ls[256], lq[256];
  ls[t] = s; lq[t] = q;
  __syncthreads();
  for (int o = 128; o; o >>= 1) {
    if (t < o) { ls[t] += ls[t + o]; lq[t] += lq[t + o]; }
    __syncthreads();
  }
  if (t == 0) {
    const float invN = 1.f / 8192.f;
    float mu  = ls[0] * invN;
    float var = fmaf(lq[0], invN, -mu * mu);
    float a = g[c] * rsqrtf(var + 1e-5f);
    ta[c] = a;
    tb[c] = fmaf(-mu, a, beta[c]);
  }
}

// ---------------------------------------------------------------------------
extern "C" void kernel_launch(void* const* d_in, const int* in_sizes, int n_in,
                              void* d_out, int out_size, void* d_ws, size_t ws_size,
                              hipStream_t stream)
{
  static const long canon_sz[23] = {
    4194304, 2048, 1048576, 262144, 512, 131072, 1024, 65536, 256,
    512, 512, 1024, 1024, 16384, 256, 32768, 128, 65536, 512,
    256, 256, 128, 128};
  static const int dict_pos[23]  = {0,1,2,3,4,5,6,7,8,9,10,11,12,
                                    13,14,15,16,17,18,19,20,21,22};
  static const int sig_pos[23]   = {0,1,2,3,4,7,8,11,12,5,6,9,10,
                                    13,14,17,18,21,22,15,16,19,20};
  static const int alpha_pos[23] = {22,21,0,11,14,12,15,13,16,19,17,20,18,
                                    1,4,2,5,3,6,9,7,10,8};
  const int* maps[3] = {dict_pos, sig_pos, alpha_pos};
  int chosen = 0;
  bool found = false;
  for (int u = 0; u < 2 && !found; ++u) {
    long unit = u ? 4 : 1;
    for (int mi = 0; mi < 3 && !found; ++mi) {
      bool ok = (n_in >= 23);
      for (int i = 0; i < 23 && ok; ++i)
        ok = ((long)in_sizes[maps[mi][i]] == canon_sz[i] * unit);
      if (ok) { chosen = mi; found = true; }
    }
  }
  const int* P = maps[chosen];
  const float* x    = (const float*)d_in[P[0]];
  const float* qt   = (const float*)d_in[P[1]];
  const float* cb   = (const float*)d_in[P[2]];
  const float* eW1  = (const float*)d_in[P[3]];
  const float* eb1  = (const float*)d_in[P[4]];
  const float* eW2  = (const float*)d_in[P[5]];
  const float* eb2  = (const float*)d_in[P[6]];
  const float* eW3  = (const float*)d_in[P[7]];
  const float* eb3  = (const float*)d_in[P[8]];
  const float* eg1  = (const float*)d_in[P[9]];
  const float* ebt1 = (const float*)d_in[P[10]];
  const float* eg2  = (const float*)d_in[P[11]];
  const float* ebt2 = (const float*)d_in[P[12]];
  const float* dW1  = (const float*)d_in[P[13]];
  const float* db1  = (const float*)d_in[P[14]];
  const float* dW2  = (const float*)d_in[P[15]];
  const float* db2  = (const float*)d_in[P[16]];
  const float* dW3  = (const float*)d_in[P[17]];
  const float* db3  = (const float*)d_in[P[18]];
  const float* dg1  = (const float*)d_in[P[19]];
  const float* dbt1 = (const float*)d_in[P[20]];
  const float* dg2  = (const float*)d_in[P[21]];
  const float* dbt2 = (const float*)d_in[P[22]];
  (void)out_size; (void)ws_size;

  float* X    = (float*)d_out;
  float* xhat = X;                         // [0, 4194304)
  float* ze   = X + 4194304;               // final output
  float* ce   = X + 6291456;               // final output
  float* pbb  = X;                         // DSPLIT*4*8192 = 524288 floats
  int*   pbk  = (int*)(X + 524288);        // 524288 ints -> ends 1048576
  float* hd1  = X;                         // decoder scratch (after gather)

  // d_ws layout (floats), total ~50.6 MB:
  float* W_   = (float*)d_ws;
  float* h1T  = W_;                        // 4,194,304  [m][128][8192]
  float* h2T  = W_ + 4194304;              // 8,388,608  [m][256][8192]
  float* cn   = W_ + 12582912;             // 16,384
  int*   idx  = (int*)(W_ + 12599296);     // 32,768 ints
  float* mu1  = W_ + 12632064;             // 512
  float* rsq1 = W_ + 12632576;             // 512
  float* mu2  = W_ + 12633088;             // 1024
  float* rsq2 = W_ + 12634112;             // 1024
  float* ad1  = W_ + 12635136;             // 256
  float* bd1  = W_ + 12635392;             // 256
  float* ad2  = W_ + 12635648;             // 128
  float* bd2  = W_ + 12635776;             // 128
  float* hd2  = W_ + 4194304;              // decoder: reuse h2T region (dead)

  cnorm_mimic_k<<<64, 256, 0, stream>>>(cb, cn);

  // encoder, all 4 books in parallel; activations stored transposed
  l1_mimic_k<<<dim3(256, 4), 256, 0, stream>>>(x, qt, eW1, eb1, h1T);
  bn_stats_t<<<dim3(128, 4), 256, 0, stream>>>(h1T, 128, mu1, rsq1);
  seq_mm2_k<<<dim3(512, 4), 256, 0, stream>>>(
      h1T, eW2, eb2, h2T, mu1, rsq1, eg1, ebt1);
  bn_stats_t<<<dim3(256, 4), 256, 0, stream>>>(h2T, 256, mu2, rsq2);
  seq_mm_k<64, 256, 4><<<dim3(256, 4), 256, 0, stream>>>(
      h2T, eW3, eb3, ze, 16384, 64, 524288, mu2, rsq2, eg2, ebt2);

  dist_mimic_k<<<dim3(32, 4, DSPLIT), 256, 0, stream>>>(ze, cb, cn, pbb, pbk);
  dist_reduce_k<<<128, 256, 0, stream>>>(pbb, pbk, idx);
  gather_k<<<512, 256, 0, stream>>>(cb, idx, ce);

  // decoder (fast fp32): L1 sums the 4 ce books on the fly
  gemm_k<2><<<dim3(4, 64), 256, 0, stream>>>(
      ce, 64, 524288, dW1, 256, db1, nullptr, nullptr, hd1, 256, 64);
  dstats_k<<<256, 256, 0, stream>>>(hd1, 256, dg1, dbt1, ad1, bd1);

  gemm_k<1><<<dim3(2, 64), 256, 0, stream>>>(
      hd1, 256, 0, dW2, 128, db2, ad1, bd1, hd2, 128, 256);
  dstats_k<<<128, 256, 0, stream>>>(hd2, 128, dg2, dbt2, ad2, bd2);

  gemm_k<1><<<dim3(8, 64), 256, 0, stream>>>(
      hd2, 128, 0, dW3, 512, db3, ad2, bd2, xhat, 512, 128);
}

// Round 19
// 847.871 us; speedup vs baseline: 1.0337x; 1.0337x over previous
//
#include <hip/hip_runtime.h>
#include <cstdint>
#include <cstddef>

// ---------------------------------------------------------------------------
// Sizes: BATCH=8192, INPUT_DIM=512, DIM=64, N_EMB=4096, M_BOOK=4
// d_out (fp32): x_hat[8192*512] | ze[4*8192*64] | ce[4*8192*64]
// Bit-exact numpy-fp32 mimic (identical FP op sequence per output to rounds
// 6-18).  This round: keep l1 shared-prefix factoring (round-18 win, ~25us);
// REVERT dist to 2 codes/iter (round-17 body; 4 codes/iter lengthened the
// per-iter critical path and cost +32us).
// ---------------------------------------------------------------------------

#define FMUL __fmul_rn
#define FADD __fadd_rn
#define FSUB __fsub_rn
#define DSPLIT 16
#define KEEP4(v) asm volatile("" : "+v"(v.x), "+v"(v.y), "+v"(v.z), "+v"(v.w))

// ---- L1 mimic: 32 rows/block, shared q-prefix -> h1T[m][h][n] ---------------
__global__ __launch_bounds__(256) void l1_mimic_k(
    const float* __restrict__ x, const float* __restrict__ qt,
    const float* __restrict__ eW1, const float* __restrict__ eb1,
    float* __restrict__ h1T)
{
  __shared__ float xL[32 * 128];
  __shared__ float qtL[512];
  const int m = blockIdx.y;
  const int t = threadIdx.x;
  const int h = t & 127, ngl = t >> 7;          // 2 groups x 16 rows
  const int n0 = blockIdx.x * 32;
  if (t < 128)
    *(float4*)&qtL[t * 4] = *(const float4*)(qt + (size_t)m * 512 + t * 4);
  for (int f4 = t; f4 < 1024; f4 += 256) {      // 32 rows x 128 cols / 4
    int r = f4 >> 5, c4 = (f4 & 31) * 4;
    *(float4*)&xL[r * 128 + c4] =
        *(const float4*)(x + (size_t)(n0 + r) * 512 + m * 128 + c4);
  }
  __syncthreads();
  const float* W1m = eW1 + (size_t)m * 65536;
  const int rbase = ngl * 16;
  const int e0 = m * 128;

  // shared prefix: e in [0, m*128), q-only terms (row-independent chain)
  float pref = 0.f;
  for (int e = 0; e < e0; e += 4) {
    float w0 = W1m[(e + 0) * 128 + h];
    float w1 = W1m[(e + 1) * 128 + h];
    float w2 = W1m[(e + 2) * 128 + h];
    float w3 = W1m[(e + 3) * 128 + h];
    float4 q4 = *(const float4*)&qtL[e];
    pref = FADD(pref, FMUL(q4.x, w0));
    pref = FADD(pref, FMUL(q4.y, w1));
    pref = FADD(pref, FMUL(q4.z, w2));
    pref = FADD(pref, FMUL(q4.w, w3));
  }
  float acc[16];
  #pragma unroll
  for (int r = 0; r < 16; ++r) acc[r] = pref;

  // patch segment: e in [m*128, m*128+128) -> row-specific x-terms
  for (int eo = 0; eo < 128; eo += 4) {
    const int e = e0 + eo;
    float w0 = W1m[(e + 0) * 128 + h];
    float w1 = W1m[(e + 1) * 128 + h];
    float w2 = W1m[(e + 2) * 128 + h];
    float w3 = W1m[(e + 3) * 128 + h];
    float4 q4 = *(const float4*)&qtL[e];
    #pragma unroll
    for (int r = 0; r < 16; ++r) {              // chain order: e ascending
      float4 x4 = *(const float4*)&xL[(rbase + r) * 128 + eo];
      acc[r] = FADD(acc[r], FMUL(FADD(x4.x, q4.x), w0));
      acc[r] = FADD(acc[r], FMUL(FADD(x4.y, q4.y), w1));
      acc[r] = FADD(acc[r], FMUL(FADD(x4.z, q4.z), w2));
      acc[r] = FADD(acc[r], FMUL(FADD(x4.w, q4.w), w3));
    }
  }

  // suffix: e in [m*128+128, 512), q-only addends (per-row chains continue)
  for (int e = e0 + 128; e < 512; e += 4) {
    float w0 = W1m[(e + 0) * 128 + h];
    float w1 = W1m[(e + 1) * 128 + h];
    float w2 = W1m[(e + 2) * 128 + h];
    float w3 = W1m[(e + 3) * 128 + h];
    float4 q4 = *(const float4*)&qtL[e];
    #pragma unroll
    for (int r = 0; r < 16; ++r) {
      acc[r] = FADD(acc[r], FMUL(q4.x, w0));
      acc[r] = FADD(acc[r], FMUL(q4.y, w1));
      acc[r] = FADD(acc[r], FMUL(q4.z, w2));
      acc[r] = FADD(acc[r], FMUL(q4.w, w3));
    }
  }

  float b = eb1[m * 128 + h];
  float* oT = h1T + ((size_t)(m * 128 + h)) * 8192 + n0 + rbase;
  #pragma unroll
  for (int j = 0; j < 4; ++j) {
    float4 o = {FADD(acc[4 * j + 0], b), FADD(acc[4 * j + 1], b),
                FADD(acc[4 * j + 2], b), FADD(acc[4 * j + 3], b)};
    *(float4*)(oT + 4 * j) = o;
  }
}

// ---- L2 GEMM mimic: OUTC=256, K=128, 16 rows/block, BN fused, out transposed
__global__ __launch_bounds__(256) void seq_mm2_k(
    const float* __restrict__ AT, const float* __restrict__ W,
    const float* __restrict__ b, float* __restrict__ outT,
    const float* __restrict__ mu, const float* __restrict__ rsq,
    const float* __restrict__ g, const float* __restrict__ beta)
{
  __shared__ float aL[16 * 128];
  const int m = blockIdx.y;
  const int t = threadIdx.x;                    // h = t, 0..255
  const int n0 = blockIdx.x * 16;
  const int mK = m * 128;
  for (int f4 = t; f4 < 512; f4 += 256) {
    int c = f4 & 127, r4 = f4 >> 7;
    float4 v = *(const float4*)(AT + (size_t)(mK + c) * 8192 + n0 + r4 * 4);
    float muv = mu[mK + c], rs = rsq[mK + c];
    float gg = g[mK + c], bt = beta[mK + c];
    v.x = fmaxf(FADD(FMUL(FMUL(FSUB(v.x, muv), rs), gg), bt), 0.f);
    v.y = fmaxf(FADD(FMUL(FMUL(FSUB(v.y, muv), rs), gg), bt), 0.f);
    v.z = fmaxf(FADD(FMUL(FMUL(FSUB(v.z, muv), rs), gg), bt), 0.f);
    v.w = fmaxf(FADD(FMUL(FMUL(FSUB(v.w, muv), rs), gg), bt), 0.f);
    aL[(r4 * 4 + 0) * 128 + c] = v.x;
    aL[(r4 * 4 + 1) * 128 + c] = v.y;
    aL[(r4 * 4 + 2) * 128 + c] = v.z;
    aL[(r4 * 4 + 3) * 128 + c] = v.w;
  }
  __syncthreads();
  const float* Wm = W + (size_t)m * 32768;
  float acc[16];
  #pragma unroll
  for (int r = 0; r < 16; ++r) acc[r] = 0.f;
  float w0n = Wm[t], w1n = Wm[256 + t], w2n = Wm[512 + t], w3n = Wm[768 + t];
  for (int e = 0; e < 128; e += 4) {
    float w0 = w0n, w1 = w1n, w2 = w2n, w3 = w3n;
    if (e < 124) {
      w0n = Wm[(e + 4) * 256 + t];
      w1n = Wm[(e + 5) * 256 + t];
      w2n = Wm[(e + 6) * 256 + t];
      w3n = Wm[(e + 7) * 256 + t];
    }
    #pragma unroll
    for (int r = 0; r < 16; ++r) {              // chain order: e ascending
      float4 a4 = *(const float4*)&aL[r * 128 + e];
      acc[r] = FADD(acc[r], FMUL(a4.x, w0));
      acc[r] = FADD(acc[r], FMUL(a4.y, w1));
      acc[r] = FADD(acc[r], FMUL(a4.z, w2));
      acc[r] = FADD(acc[r], FMUL(a4.w, w3));
    }
  }
  float bb = b[m * 256 + t];
  float* oT = outT + (size_t)(m * 256 + t) * 8192 + n0;
  #pragma unroll
  for (int j = 0; j < 4; ++j) {
    float4 o = {FADD(acc[4 * j + 0], bb), FADD(acc[4 * j + 1], bb),
                FADD(acc[4 * j + 2], bb), FADD(acc[4 * j + 3], bb)};
    *(float4*)(oT + 4 * j) = o;
  }
}

// ---- L3 GEMM mimic (generic): from transposed A, BN fused, row-major out ---
template <int OUTC, int K, int RG>
__global__ __launch_bounds__(256) void seq_mm_k(
    const float* __restrict__ AT, const float* __restrict__ W,
    const float* __restrict__ b, float* __restrict__ out,
    long w_bs, long b_bs, long o_bs,
    const float* __restrict__ mu, const float* __restrict__ rsq,
    const float* __restrict__ g, const float* __restrict__ beta)
{
  __shared__ float aL[RG * 8 * K];
  const int m = blockIdx.y;
  const int t = threadIdx.x;
  const int h = t % OUTC, ngl = t / OUTC;
  const int n0 = blockIdx.x * RG * 8;
  const int mK = m * K;
  for (int f4 = t; f4 < K * 2 * RG; f4 += 256) {
    int c = f4 % K, r4 = f4 / K;
    float4 v = *(const float4*)(AT + (size_t)(mK + c) * 8192 + n0 + r4 * 4);
    float muv = mu[mK + c], rs = rsq[mK + c];
    float gg = g[mK + c], bt = beta[mK + c];
    v.x = fmaxf(FADD(FMUL(FMUL(FSUB(v.x, muv), rs), gg), bt), 0.f);
    v.y = fmaxf(FADD(FMUL(FMUL(FSUB(v.y, muv), rs), gg), bt), 0.f);
    v.z = fmaxf(FADD(FMUL(FMUL(FSUB(v.z, muv), rs), gg), bt), 0.f);
    v.w = fmaxf(FADD(FMUL(FMUL(FSUB(v.w, muv), rs), gg), bt), 0.f);
    aL[(r4 * 4 + 0) * K + c] = v.x;
    aL[(r4 * 4 + 1) * K + c] = v.y;
    aL[(r4 * 4 + 2) * K + c] = v.z;
    aL[(r4 * 4 + 3) * K + c] = v.w;
  }
  __syncthreads();
  const float* Wm = W + (size_t)m * w_bs;
  float acc[8] = {0.f,0.f,0.f,0.f,0.f,0.f,0.f,0.f};
  float w0n = Wm[h], w1n = Wm[OUTC + h], w2n = Wm[2 * OUTC + h],
        w3n = Wm[3 * OUTC + h];
  for (int e = 0; e < K; e += 4) {
    float w0 = w0n, w1 = w1n, w2 = w2n, w3 = w3n;
    if (e < K - 4) {
      w0n = Wm[(e + 4) * OUTC + h];
      w1n = Wm[(e + 5) * OUTC + h];
      w2n = Wm[(e + 6) * OUTC + h];
      w3n = Wm[(e + 7) * OUTC + h];
    }
    float4 a4[8];
    #pragma unroll
    for (int r = 0; r < 8; ++r)
      a4[r] = *(const float4*)&aL[(ngl * 8 + r) * K + e];
    #pragma unroll
    for (int r = 0; r < 8; ++r) {               // chain order: e ascending
      acc[r] = FADD(acc[r], FMUL(a4[r].x, w0));
      acc[r] = FADD(acc[r], FMUL(a4[r].y, w1));
      acc[r] = FADD(acc[r], FMUL(a4[r].z, w2));
      acc[r] = FADD(acc[r], FMUL(a4[r].w, w3));
    }
  }
  float bb = b[(size_t)m * b_bs + h];
  #pragma unroll
  for (int r = 0; r < 8; ++r)
    out[(size_t)m * o_bs + (size_t)(n0 + ngl * 8 + r) * OUTC + h] =
        FADD(acc[r], bb);
}

// ---- BN stats from transposed h: contiguous column staged to LDS -----------
__global__ __launch_bounds__(256) void bn_stats_t(
    const float* __restrict__ hT, int K,
    float* __restrict__ mu, float* __restrict__ rsq)
{
  __shared__ float colL[8192];
  const int c = blockIdx.x, m = blockIdx.y;
  const float4* src = (const float4*)(hT + (size_t)(m * K + c) * 8192);
  for (int i = threadIdx.x; i < 2048; i += 256)
    ((float4*)colL)[i] = src[i];
  __syncthreads();
  if (threadIdx.x == 0) {
    float s = 0.f;
    for (int n = 0; n < 8192; ++n) s = FADD(s, colL[n]);
    float muv = __fdiv_rn(s, 8192.f);
    float q = 0.f;
    for (int n = 0; n < 8192; ++n) {
      float d = FSUB(colL[n], muv);
      q = FADD(q, FMUL(d, d));
    }
    float var = __fdiv_rn(q, 8192.f);
    mu[m * K + c] = muv;
    rsq[m * K + c] = __fdiv_rn(1.f, __fsqrt_rn(FADD(var, 1e-5f)));
  }
}

// ---- cnorm mimic: numpy pairwise 8-accumulator sum of c^2 ------------------
__global__ __launch_bounds__(256) void cnorm_mimic_k(
    const float* __restrict__ cb, float* __restrict__ cn)
{
  int o = blockIdx.x * 256 + threadIdx.x;
  const float* c = cb + (size_t)o * 64;
  float r[8];
  #pragma unroll
  for (int j = 0; j < 8; ++j) r[j] = FMUL(c[j], c[j]);
  for (int t = 1; t < 8; ++t)
    #pragma unroll
    for (int j = 0; j < 8; ++j)
      r[j] = FADD(r[j], FMUL(c[8 * t + j], c[8 * t + j]));
  cn[o] = FADD(FADD(FADD(r[0], r[1]), FADD(r[2], r[3])),
               FADD(FADD(r[4], r[5]), FADD(r[6], r[7])));
}

// ---- distance + argmin mimic: GLOBAL code reads, z in regs, 2 codes/iter ---
__global__ __launch_bounds__(256, 4) void dist_mimic_k(
    const float* __restrict__ ze, const float* __restrict__ cb,
    const float* __restrict__ cn, float* __restrict__ pbb,
    int* __restrict__ pbk)
{
  const int t = threadIdx.x;
  const int m = blockIdx.y, seg = blockIdx.z;
  const int n = blockIdx.x * 256 + t;
  const float4* zp4 = (const float4*)(ze + ((size_t)m * 8192 + n) * 64);
  float4 z0 = zp4[0],  z1 = zp4[1],  z2 = zp4[2],  z3 = zp4[3];
  float4 z4 = zp4[4],  z5 = zp4[5],  z6 = zp4[6],  z7 = zp4[7];
  float4 z8 = zp4[8],  z9 = zp4[9],  z10 = zp4[10], z11 = zp4[11];
  float4 z12 = zp4[12], z13 = zp4[13], z14 = zp4[14], z15 = zp4[15];

  // t1 = numpy pairwise-8 sum of squares (identical order since round 6)
  float r0 = FMUL(z0.x, z0.x), r1 = FMUL(z0.y, z0.y);
  float r2 = FMUL(z0.z, z0.z), r3 = FMUL(z0.w, z0.w);
  float r4 = FMUL(z1.x, z1.x), r5 = FMUL(z1.y, z1.y);
  float r6 = FMUL(z1.z, z1.z), r7 = FMUL(z1.w, z1.w);
#define SQ8(ZE, ZO) \
  r0 = FADD(r0, FMUL(ZE.x, ZE.x)); r1 = FADD(r1, FMUL(ZE.y, ZE.y)); \
  r2 = FADD(r2, FMUL(ZE.z, ZE.z)); r3 = FADD(r3, FMUL(ZE.w, ZE.w)); \
  r4 = FADD(r4, FMUL(ZO.x, ZO.x)); r5 = FADD(r5, FMUL(ZO.y, ZO.y)); \
  r6 = FADD(r6, FMUL(ZO.z, ZO.z)); r7 = FADD(r7, FMUL(ZO.w, ZO.w));
  SQ8(z2, z3)  SQ8(z4, z5)  SQ8(z6, z7)
  SQ8(z8, z9)  SQ8(z10, z11) SQ8(z12, z13) SQ8(z14, z15)
#undef SQ8
  const float t1 = FADD(FADD(FADD(r0, r1), FADD(r2, r3)),
                        FADD(FADD(r4, r5), FADD(r6, r7)));

  // force z into registers (defeat rematerialization-from-global)
  KEEP4(z0);  KEEP4(z1);  KEEP4(z2);  KEEP4(z3);
  KEEP4(z4);  KEEP4(z5);  KEEP4(z6);  KEEP4(z7);
  KEEP4(z8);  KEEP4(z9);  KEEP4(z10); KEEP4(z11);
  KEEP4(z12); KEEP4(z13); KEEP4(z14); KEEP4(z15);

  const float* cbm = cb + (size_t)m * 262144;
  const float* cnm = cn + m * 4096;
  float bb = 3.4e38f;
  int bk = 1 << 30;
  const int k0 = seg * (4096 / DSPLIT);
  for (int k = k0; k < k0 + 4096 / DSPLIT; k += 2) {
    const float4* ca4 = (const float4*)(cbm + (size_t)k * 64);
    const float4* cb4 = ca4 + 16;
    float A0 = 0.f, A1 = 0.f, A2 = 0.f, A3 = 0.f;
    float B0 = 0.f, B1 = 0.f, B2 = 0.f, B3 = 0.f;
#define DOTSTEP(ZV, S) { \
    float4 ca_ = ca4[S]; float4 cbv_ = cb4[S]; \
    A0 = FADD(A0, FMUL(ZV.x, ca_.x)); B0 = FADD(B0, FMUL(ZV.x, cbv_.x)); \
    A1 = FADD(A1, FMUL(ZV.y, ca_.y)); B1 = FADD(B1, FMUL(ZV.y, cbv_.y)); \
    A2 = FADD(A2, FMUL(ZV.z, ca_.z)); B2 = FADD(B2, FMUL(ZV.z, cbv_.z)); \
    A3 = FADD(A3, FMUL(ZV.w, ca_.w)); B3 = FADD(B3, FMUL(ZV.w, cbv_.w)); }
    DOTSTEP(z0, 0)   DOTSTEP(z1, 1)   DOTSTEP(z2, 2)   DOTSTEP(z3, 3)
    DOTSTEP(z4, 4)   DOTSTEP(z5, 5)   DOTSTEP(z6, 6)   DOTSTEP(z7, 7)
    DOTSTEP(z8, 8)   DOTSTEP(z9, 9)   DOTSTEP(z10, 10) DOTSTEP(z11, 11)
    DOTSTEP(z12, 12) DOTSTEP(z13, 13) DOTSTEP(z14, 14) DOTSTEP(z15, 15)
#undef DOTSTEP
    float dotA = FADD(FADD(A0, A2), FADD(A1, A3));
    float bA = FADD(FSUB(t1, FMUL(2.f, dotA)), cnm[k]);
    if (bA < bb) { bb = bA; bk = k; }
    float dotB = FADD(FADD(B0, B2), FADD(B1, B3));
    float bB = FADD(FSUB(t1, FMUL(2.f, dotB)), cnm[k + 1]);
    if (bB < bb) { bb = bB; bk = k + 1; }
  }
  size_t o = ((size_t)seg * 4 + m) * 8192 + n;
  pbb[o] = bb;
  pbk[o] = bk;
}

// ---- combine segment partials (ascending seg = ascending k) ----------------
__global__ __launch_bounds__(256) void dist_reduce_k(
    const float* __restrict__ pbb, const int* __restrict__ pbk,
    int* __restrict__ idx)
{
  int i = blockIdx.x * 256 + threadIdx.x;        // 32768 = m*8192+n
  int m = i >> 13, n = i & 8191;
  float bb = pbb[(size_t)m * 8192 + n];
  int bk = pbk[(size_t)m * 8192 + n];
  for (int s = 1; s < DSPLIT; ++s) {
    size_t o = ((size_t)s * 4 + m) * 8192 + n;
    float ob = pbb[o];
    if (ob < bb) { bb = ob; bk = pbk[o]; }
  }
  idx[(size_t)m * 8192 + n] = bk;
}

// ---- gather ce --------------------------------------------------------------
__global__ __launch_bounds__(256) void gather_k(
    const float* __restrict__ cb, const int* __restrict__ idx,
    float* __restrict__ ce)
{
  int t = threadIdx.x;
  int n = blockIdx.x * 16 + (t >> 4);
  int j = t & 15;
  #pragma unroll
  for (int m = 0; m < 4; ++m) {
    int k = idx[(size_t)m * 8192 + n];
    float4 v = *(const float4*)(cb + ((size_t)m * 4096 + k) * 64 + j * 4);
    *(float4*)(ce + ((size_t)m * 8192 + n) * 64 + j * 4) = v;
  }
}

// ---- fast fp32 GEMM (decoder; loose tolerance) ------------------------------
template <int TRANS>
__global__ __launch_bounds__(256) void gemm_k(
    const float* __restrict__ A, int lda, long cst,
    const float* __restrict__ B, int ldb,
    const float* __restrict__ bias,
    const float* __restrict__ ta, const float* __restrict__ tb,
    float* __restrict__ C, int ldc, int K)
{
  __shared__ float As[16][132];
  __shared__ float Bs[16][64];
  const int tid  = threadIdx.x;
  const int row0 = blockIdx.y * 128;
  const int col0 = blockIdx.x * 64;
  const int tr = tid >> 4, tc = tid & 15;
  const int arow = tid >> 2, ak = (tid & 3) * 4;
  const int brow = tid >> 4, bcol = (tid & 15) * 4;

  float acc[8][4];
  #pragma unroll
  for (int i = 0; i < 8; ++i)
    #pragma unroll
    for (int j = 0; j < 4; ++j) acc[i][j] = 0.f;

  for (int k0 = 0; k0 < K; k0 += 16) {
    #pragma unroll
    for (int h = 0; h < 2; ++h) {
      int r = arow + h * 64;
      float4 v;
      if (TRANS == 2) {
        const float* p = A + (size_t)(row0 + r) * lda + k0 + ak;
        float4 u0 = *(const float4*)(p);
        float4 u1 = *(const float4*)(p + cst);
        float4 u2 = *(const float4*)(p + 2 * cst);
        float4 u3 = *(const float4*)(p + 3 * cst);
        v.x = u0.x + u1.x + u2.x + u3.x;
        v.y = u0.y + u1.y + u2.y + u3.y;
        v.z = u0.z + u1.z + u2.z + u3.z;
        v.w = u0.w + u1.w + u2.w + u3.w;
      } else {
        v = *(const float4*)(A + (size_t)(row0 + r) * lda + k0 + ak);
      }
      if (TRANS == 1) {
        v.x = fmaxf(fmaf(ta[k0 + ak + 0], v.x, tb[k0 + ak + 0]), 0.f);
        v.y = fmaxf(fmaf(ta[k0 + ak + 1], v.y, tb[k0 + ak + 1]), 0.f);
        v.z = fmaxf(fmaf(ta[k0 + ak + 2], v.z, tb[k0 + ak + 2]), 0.f);
        v.w = fmaxf(fmaf(ta[k0 + ak + 3], v.w, tb[k0 + ak + 3]), 0.f);
      }
      As[ak + 0][r] = v.x; As[ak + 1][r] = v.y;
      As[ak + 2][r] = v.z; As[ak + 3][r] = v.w;
    }
    *(float4*)&Bs[brow][bcol] =
        *(const float4*)(B + (size_t)(k0 + brow) * ldb + col0 + bcol);
    __syncthreads();
    #pragma unroll
    for (int kk = 0; kk < 16; ++kk) {
      float4 b4 = *(float4*)&Bs[kk][tc * 4];
      float4 a0 = *(float4*)&As[kk][tr * 8];
      float4 a1 = *(float4*)&As[kk][tr * 8 + 4];
      float a8[8] = {a0.x, a0.y, a0.z, a0.w, a1.x, a1.y, a1.z, a1.w};
      #pragma unroll
      for (int i = 0; i < 8; ++i) {
        acc[i][0] = fmaf(a8[i], b4.x, acc[i][0]);
        acc[i][1] = fmaf(a8[i], b4.y, acc[i][1]);
        acc[i][2] = fmaf(a8[i], b4.z, acc[i][2]);
        acc[i][3] = fmaf(a8[i], b4.w, acc[i][3]);
      }
    }
    __syncthreads();
  }
  float4 bv = *(const float4*)(bias + col0 + tc * 4);
  float* Cp = C + (size_t)(row0 + tr * 8) * ldc + col0 + tc * 4;
  #pragma unroll
  for (int i = 0; i < 8; ++i) {
    float4 o;
    o.x = acc[i][0] + bv.x; o.y = acc[i][1] + bv.y;
    o.z = acc[i][2] + bv.z; o.w = acc[i][3] + bv.w;
    *(float4*)(Cp + (size_t)i * ldc) = o;
  }
}

// ---- decoder BN stats: single kernel, one block per column -----------------
__global__ __launch_bounds__(256) void dstats_k(
    const float* __restrict__ A, int cols, const float* __restrict__ g,
    const float* __restrict__ beta, float* __restrict__ ta,
    float* __restrict__ tb)
{
  const int c = blockIdx.x, t = threadIdx.x;
  float s = 0.f, q = 0.f;
  for (int n = t; n < 8192; n += 256) {
    float v = A[(size_t)n * cols + c];
    s += v;
    q = fmaf(v, v, q);
  }
  __shared__ float ls[256], lq[256];
  ls[t] = s; lq[t] = q;
  __syncthreads();
  for (int o = 128; o; o >>= 1) {
    if (t < o) { ls[t] += ls[t + o]; lq[t] += lq[t + o]; }
    __syncthreads();
  }
  if (t == 0) {
    const float invN = 1.f / 8192.f;
    float mu  = ls[0] * invN;
    float var = fmaf(lq[0], invN, -mu * mu);
    float a = g[c] * rsqrtf(var + 1e-5f);
    ta[c] = a;
    tb[c] = fmaf(-mu, a, beta[c]);
  }
}

// ---------------------------------------------------------------------------
extern "C" void kernel_launch(void* const* d_in, const int* in_sizes, int n_in,
                              void* d_out, int out_size, void* d_ws, size_t ws_size,
                              hipStream_t stream)
{
  static const long canon_sz[23] = {
    4194304, 2048, 1048576, 262144, 512, 131072, 1024, 65536, 256,
    512, 512, 1024, 1024, 16384, 256, 32768, 128, 65536, 512,
    256, 256, 128, 128};
  static const int dict_pos[23]  = {0,1,2,3,4,5,6,7,8,9,10,11,12,
                                    13,14,15,16,17,18,19,20,21,22};
  static const int sig_pos[23]   = {0,1,2,3,4,7,8,11,12,5,6,9,10,
                                    13,14,17,18,21,22,15,16,19,20};
  static const int alpha_pos[23] = {22,21,0,11,14,12,15,13,16,19,17,20,18,
                                    1,4,2,5,3,6,9,7,10,8};
  const int* maps[3] = {dict_pos, sig_pos, alpha_pos};
  int chosen = 0;
  bool found = false;
  for (int u = 0; u < 2 && !found; ++u) {
    long unit = u ? 4 : 1;
    for (int mi = 0; mi < 3 && !found; ++mi) {
      bool ok = (n_in >= 23);
      for (int i = 0; i < 23 && ok; ++i)
        ok = ((long)in_sizes[maps[mi][i]] == canon_sz[i] * unit);
      if (ok) { chosen = mi; found = true; }
    }
  }
  const int* P = maps[chosen];
  const float* x    = (const float*)d_in[P[0]];
  const float* qt   = (const float*)d_in[P[1]];
  const float* cb   = (const float*)d_in[P[2]];
  const float* eW1  = (const float*)d_in[P[3]];
  const float* eb1  = (const float*)d_in[P[4]];
  const float* eW2  = (const float*)d_in[P[5]];
  const float* eb2  = (const float*)d_in[P[6]];
  const float* eW3  = (const float*)d_in[P[7]];
  const float* eb3  = (const float*)d_in[P[8]];
  const float* eg1  = (const float*)d_in[P[9]];
  const float* ebt1 = (const float*)d_in[P[10]];
  const float* eg2  = (const float*)d_in[P[11]];
  const float* ebt2 = (const float*)d_in[P[12]];
  const float* dW1  = (const float*)d_in[P[13]];
  const float* db1  = (const float*)d_in[P[14]];
  const float* dW2  = (const float*)d_in[P[15]];
  const float* db2  = (const float*)d_in[P[16]];
  const float* dW3  = (const float*)d_in[P[17]];
  const float* db3  = (const float*)d_in[P[18]];
  const float* dg1  = (const float*)d_in[P[19]];
  const float* dbt1 = (const float*)d_in[P[20]];
  const float* dg2  = (const float*)d_in[P[21]];
  const float* dbt2 = (const float*)d_in[P[22]];
  (void)out_size; (void)ws_size;

  float* X    = (float*)d_out;
  float* xhat = X;                         // [0, 4194304)
  float* ze   = X + 4194304;               // final output
  float* ce   = X + 6291456;               // final output
  float* pbb  = X;                         // DSPLIT*4*8192 = 524288 floats
  int*   pbk  = (int*)(X + 524288);        // 524288 ints -> ends 1048576
  float* hd1  = X;                         // decoder scratch (after gather)

  // d_ws layout (floats), total ~50.6 MB:
  float* W_   = (float*)d_ws;
  float* h1T  = W_;                        // 4,194,304  [m][128][8192]
  float* h2T  = W_ + 4194304;              // 8,388,608  [m][256][8192]
  float* cn   = W_ + 12582912;             // 16,384
  int*   idx  = (int*)(W_ + 12599296);     // 32,768 ints
  float* mu1  = W_ + 12632064;             // 512
  float* rsq1 = W_ + 12632576;             // 512
  float* mu2  = W_ + 12633088;             // 1024
  float* rsq2 = W_ + 12634112;             // 1024
  float* ad1  = W_ + 12635136;             // 256
  float* bd1  = W_ + 12635392;             // 256
  float* ad2  = W_ + 12635648;             // 128
  float* bd2  = W_ + 12635776;             // 128
  float* hd2  = W_ + 4194304;              // decoder: reuse h2T region (dead)

  cnorm_mimic_k<<<64, 256, 0, stream>>>(cb, cn);

  // encoder, all 4 books in parallel; activations stored transposed
  l1_mimic_k<<<dim3(256, 4), 256, 0, stream>>>(x, qt, eW1, eb1, h1T);
  bn_stats_t<<<dim3(128, 4), 256, 0, stream>>>(h1T, 128, mu1, rsq1);
  seq_mm2_k<<<dim3(512, 4), 256, 0, stream>>>(
      h1T, eW2, eb2, h2T, mu1, rsq1, eg1, ebt1);
  bn_stats_t<<<dim3(256, 4), 256, 0, stream>>>(h2T, 256, mu2, rsq2);
  seq_mm_k<64, 256, 4><<<dim3(256, 4), 256, 0, stream>>>(
      h2T, eW3, eb3, ze, 16384, 64, 524288, mu2, rsq2, eg2, ebt2);

  dist_mimic_k<<<dim3(32, 4, DSPLIT), 256, 0, stream>>>(ze, cb, cn, pbb, pbk);
  dist_reduce_k<<<128, 256, 0, stream>>>(pbb, pbk, idx);
  gather_k<<<512, 256, 0, stream>>>(cb, idx, ce);

  // decoder (fast fp32): L1 sums the 4 ce books on the fly
  gemm_k<2><<<dim3(4, 64), 256, 0, stream>>>(
      ce, 64, 524288, dW1, 256, db1, nullptr, nullptr, hd1, 256, 64);
  dstats_k<<<256, 256, 0, stream>>>(hd1, 256, dg1, dbt1, ad1, bd1);

  gemm_k<1><<<dim3(2, 64), 256, 0, stream>>>(
      hd1, 256, 0, dW2, 128, db2, ad1, bd1, hd2, 128, 256);
  dstats_k<<<128, 256, 0, stream>>>(hd2, 128, dg2, dbt2, ad2, bd2);

  gemm_k<1><<<dim3(8, 64), 256, 0, stream>>>(
      hd2, 128, 0, dW3, 512, db3, ad2, bd2, xhat, 512, 128);
}